// Round 1
// baseline (307.756 us; speedup 1.0000x reference)
//
#include <hip/hip_runtime.h>

// Maxwell RNN scan: gamma_n = (1-h_n) gamma_{n-1} + h_n eps_n, h = 0.5*dt
// sig_n = 2.5*eps_n - gamma_{n-1}   (pre-update gamma)
// Parallelized via affine-transform composition scan within each row.

constexpr int   T_LEN   = 8192;
constexpr int   THREADS = 256;
constexpr int   V       = 8;              // elements per thread per tile
constexpr int   TILE    = THREADS * V;    // 2048
constexpr int   NTILES  = T_LEN / TILE;   // 4
constexpr int   NWAVES  = THREADS / 64;   // 4
constexpr float KCOEF   = 0.5f;           // E_MOD / ETA

__global__ __launch_bounds__(THREADS) void maxwell_scan_kernel(
    const float* __restrict__ eps, const float* __restrict__ dtv,
    float* __restrict__ out)
{
    const size_t row = (size_t)blockIdx.x * T_LEN;
    const float* e_row = eps + row;
    const float* d_row = dtv + row;
    float*       o_row = out + row;

    __shared__ float wA[NWAVES];
    __shared__ float wB[NWAVES];

    const int lane = threadIdx.x & 63;
    const int wid  = threadIdx.x >> 6;

    float gamma = 0.0f;  // carry across tiles (uniform across the block)

    for (int t = 0; t < NTILES; ++t) {
        const int base = t * TILE + threadIdx.x * V;

        // Coalesced-ish vector loads: 8 contiguous floats per thread.
        float4 e0 = *(const float4*)(e_row + base);
        float4 e1 = *(const float4*)(e_row + base + 4);
        float4 d0 = *(const float4*)(d_row + base);
        float4 d1 = *(const float4*)(d_row + base + 4);
        float ev[V] = {e0.x, e0.y, e0.z, e0.w, e1.x, e1.y, e1.z, e1.w};
        float hv[V] = {d0.x * KCOEF, d0.y * KCOEF, d0.z * KCOEF, d0.w * KCOEF,
                       d1.x * KCOEF, d1.y * KCOEF, d1.z * KCOEF, d1.w * KCOEF};

        // Compose this thread's chunk: gamma_out = A*gamma_in + Bc
        float A = 1.0f, Bc = 0.0f;
        #pragma unroll
        for (int j = 0; j < V; ++j) {
            float a = 1.0f - hv[j];
            Bc = a * Bc + hv[j] * ev[j];
            A  = a * A;
        }

        // Inclusive wave scan under composition (later ∘ earlier).
        float sa = A, sb = Bc;
        #pragma unroll
        for (int off = 1; off < 64; off <<= 1) {
            float pa = __shfl_up(sa, off, 64);
            float pb = __shfl_up(sb, off, 64);
            if (lane >= off) {
                sb = sa * pb + sb;
                sa = sa * pa;
            }
        }
        if (lane == 63) { wA[wid] = sa; wB[wid] = sb; }
        __syncthreads();

        // Exclusive-within-wave transform.
        float ea = __shfl_up(sa, 1, 64);
        float eb = __shfl_up(sb, 1, 64);
        if (lane == 0) { ea = 1.0f; eb = 0.0f; }

        // Prefix over preceding waves (pa,pb) and block total (ta,tb).
        float pfa = 1.0f, pfb = 0.0f;
        float ta  = 1.0f, tb  = 0.0f;
        #pragma unroll
        for (int w = 0; w < NWAVES; ++w) {
            float a = wA[w], bb = wB[w];
            if (w < wid) { pfb = a * pfb + bb; pfa = a * pfa; }
            tb = a * tb + bb;
            ta = a * ta;
        }

        // Thread's exclusive block transform, applied to the tile-entering gamma.
        float xa = ea * pfa;
        float xb = ea * pfb + eb;
        float g  = xa * gamma + xb;   // gamma entering this thread's chunk

        // Replay chunk: emit sigma, advance gamma.
        float sg[V];
        #pragma unroll
        for (int j = 0; j < V; ++j) {
            sg[j] = 2.5f * ev[j] - g;            // E_INF*e + E*(e - g)
            g = g + hv[j] * (ev[j] - g);         // g += dt*k*(e - g)
        }
        *(float4*)(o_row + base)     = make_float4(sg[0], sg[1], sg[2], sg[3]);
        *(float4*)(o_row + base + 4) = make_float4(sg[4], sg[5], sg[6], sg[7]);

        // Advance carry by the block-total transform (uniform).
        gamma = ta * gamma + tb;
        __syncthreads();  // protect wA/wB before next tile overwrites
    }
}

extern "C" void kernel_launch(void* const* d_in, const int* in_sizes, int n_in,
                              void* d_out, int out_size, void* d_ws, size_t ws_size,
                              hipStream_t stream) {
    const float* eps = (const float*)d_in[0];
    const float* dtv = (const float*)d_in[1];
    float* out = (float*)d_out;
    const int B = in_sizes[0] / T_LEN;   // 4096 rows
    maxwell_scan_kernel<<<B, THREADS, 0, stream>>>(eps, dtv, out);
}